// Round 8
// baseline (278.015 us; speedup 1.0000x reference)
//
#include <hip/hip_runtime.h>
#include <stdint.h>

#define BB 4096
#define TT 200
#define DD 128
#define HH 128

typedef __attribute__((ext_vector_type(8))) short bf16x8;
typedef __attribute__((ext_vector_type(4))) float f32x4;

__device__ __forceinline__ short f2bf(float f) {
    uint32_t u = __builtin_bit_cast(uint32_t, f);
    u += 0x7fffu + ((u >> 16) & 1u);   // RNE
    return (short)(u >> 16);
}
__device__ __forceinline__ uint32_t pk2(float a, float b) {
    uint32_t r;
    asm("v_cvt_pk_bf16_f32 %0, %1, %2" : "=v"(r) : "v"(a), "v"(b));
    return r;
}
__device__ __forceinline__ float sigm(float x) {
    return __builtin_amdgcn_rcpf(1.0f + __expf(-x));
}
__device__ __forceinline__ float tanhf_(float x) {
    return 2.0f * __builtin_amdgcn_rcpf(1.0f + __expf(-2.0f * x)) - 1.0f;
}
__device__ __forceinline__ bf16x8 mk8(float4 a, float4 b) {
    union { uint32_t u[4]; bf16x8 v; } q;
    q.u[0] = pk2(a.x, a.y); q.u[1] = pk2(a.z, a.w);
    q.u[2] = pk2(b.x, b.y); q.u[3] = pk2(b.z, b.w);
    return q.v;
}
// LDS-only barrier: drain lgkm (ds ops), NOT vmcnt -> global prefetch
// stays in flight across the barrier.
__device__ __forceinline__ void bar_lds() {
    asm volatile("s_waitcnt lgkmcnt(0)" ::: "memory");
    __builtin_amdgcn_sched_barrier(0);
    __builtin_amdgcn_s_barrier();
    __builtin_amdgcn_sched_barrier(0);
}
#define MFMA16 __builtin_amdgcn_mfma_f32_16x16x32_bf16

// Round-8: r7's producer/consumer structure with PROVEN-SAFE memory idioms.
// r7's NaN is attributed to asm global_load + manual vmcnt under ~256-VGPR
// pressure: if the compiler spills/reassigns the asm's destination before the
// load returns (it assumes asm results are synchronous), garbage materializes.
// Plain C++ prefetch loads (r0-r5, all passed) are immune: the compiler
// inserts vmcnt waits before any use OR spill. Also: __launch_bounds__(512)
// flat only (r3 lesson: never use the waves-per-EU arg).
//
// Roles: consumers (waves 0-3) hold recurrent W halves (96 VGPR), run the
// serial chain. Producers (waves 4-7) hold feed-forward W halves, compute
// pff(t+1)=b+Wx*x(t+1) one step ahead into double-buffered LDS. One wave of
// each role per SIMD -> producer work fills consumer stalls (m114).

__global__ __launch_bounds__(512) void augru_kernel(
    const float* __restrict__ inp,   // [B,T,D]
    const float* __restrict__ att,   // [B,T]
    const float* __restrict__ h0,    // [B,H]
    const float* __restrict__ Wz, const float* __restrict__ bz,
    const float* __restrict__ Wr, const float* __restrict__ br,
    const float* __restrict__ Wh, const float* __restrict__ bh,
    float* __restrict__ out)         // [B,H]
{
    __shared__ bf16x8 hbuf[16][16];        // h(t) bf16 mirror, XOR-swizzled granules
    __shared__ bf16x8 rhbuf[16][16];       // r*h staging, swizzled
    __shared__ float  pff[2][3][16][132];  // [slot][gate z,r,h][row][col], padded
    __shared__ float  attbuf[16][201];     // att tile, padded
    __shared__ float  biasLDS[3][132];     // bias broadcast source (producers)

    const int tid  = threadIdx.x;
    const int wave = tid >> 6;           // 0..7
    const int lane = tid & 63;
    const int c    = lane & 15;          // batch row
    const int grp  = lane >> 4;          // k-group
    const int wsub = wave & 3;
    const bool cons = (wave < 4);
    const int wbase = wsub * 32;         // this wave's 32 cols (both roles)
    const int rowbase = blockIdx.x * 16;

    const int swz = c & 7;
    const int fg[4] = { (0 + grp) ^ swz, (4 + grp) ^ swz,
                        (8 + grp) ^ swz, (12 + grp) ^ swz };
    const int oc[2]   = { wbase + grp * 4, wbase + 16 + grp * 4 };
    const int gout[2] = { (4 * wsub + (grp >> 1)) ^ swz,
                          (4 * wsub + 2 + (grp >> 1)) ^ swz };
    const int ohalf = (grp & 1) * 4;
    const bf16x8* hrow  = &hbuf[c][0];
    const bf16x8* rhrow = &rhbuf[c][0];

    // ---------- weights: role-dependent half (96 VGPR each) ----------
    // consumers: recurrent rows k=128..255; producers: feed-forward rows 0..127
    bf16x8 W[3][4][2];
    {
        const float* Wp3[3] = {Wz, Wr, Wh};
        const int kbase = cons ? 128 : 0;
        #pragma unroll
        for (int g3 = 0; g3 < 3; ++g3)
            #pragma unroll
            for (int kt = 0; kt < 4; ++kt)
                #pragma unroll
                for (int ct = 0; ct < 2; ++ct) {
                    bf16x8 v;
                    #pragma unroll
                    for (int j = 0; j < 8; ++j) {
                        int k = kbase + kt * 32 + grp * 8 + j;
                        v[j] = f2bf(Wp3[g3][(size_t)k * HH + wbase + ct * 16 + c]);
                    }
                    W[g3][kt][ct] = v;
                }
    }

    // ---------- att + bias staging (all 512 threads) ----------
    for (int idx = tid; idx < 16 * TT; idx += 512)
        attbuf[idx / TT][idx % TT] = att[(size_t)rowbase * TT + idx];
    {
        const float* Bp3[3] = {bz, br, bh};
        for (int idx = tid; idx < 3 * 128; idx += 512)
            biasLDS[idx >> 7][idx & 127] = Bp3[idx >> 7][idx & 127];
    }

    f32x4 hreg[2];
    float4 S[8];   // producer x-prefetch regs (x(t+1) for next step)
    const float* xsrcP = inp + (size_t)(rowbase + c) * TT * DD + grp * 8;

    if (cons) {
        // ---------- h state ----------
        #pragma unroll
        for (int ct = 0; ct < 2; ++ct) {
            float4 hv = *(const float4*)&h0[(size_t)(rowbase + c) * HH + oc[ct]];
            hreg[ct][0] = hv.x; hreg[ct][1] = hv.y; hreg[ct][2] = hv.z; hreg[ct][3] = hv.w;
            *(uint2*)((short*)&hbuf[c][gout[ct]] + ohalf) =
                make_uint2(pk2(hv.x, hv.y), pk2(hv.z, hv.w));
        }
    } else {
        // ---------- pff(0) from x(0) ----------
        f32x4 paz[2], par[2], pah[2];
        #pragma unroll
        for (int ct = 0; ct < 2; ++ct) {
            paz[ct] = *(const f32x4*)&bz[oc[ct]];
            par[ct] = *(const f32x4*)&br[oc[ct]];
            pah[ct] = *(const f32x4*)&bh[oc[ct]];
        }
        bf16x8 xf0[4];
        #pragma unroll
        for (int kt = 0; kt < 4; ++kt) {
            float4 a = *(const float4*)(xsrcP + kt * 32);
            float4 b = *(const float4*)(xsrcP + kt * 32 + 4);
            xf0[kt] = mk8(a, b);
        }
        #pragma unroll
        for (int kt = 0; kt < 4; ++kt)
            #pragma unroll
            for (int ct = 0; ct < 2; ++ct) {
                paz[ct] = MFMA16(W[0][kt][ct], xf0[kt], paz[ct], 0, 0, 0);
                par[ct] = MFMA16(W[1][kt][ct], xf0[kt], par[ct], 0, 0, 0);
                pah[ct] = MFMA16(W[2][kt][ct], xf0[kt], pah[ct], 0, 0, 0);
            }
        #pragma unroll
        for (int ct = 0; ct < 2; ++ct) {
            *(f32x4*)&pff[0][0][c][oc[ct]] = paz[ct];
            *(f32x4*)&pff[0][1][c][oc[ct]] = par[ct];
            *(f32x4*)&pff[0][2][c][oc[ct]] = pah[ct];
        }
        // prefetch x(1) -> S (plain loads; compiler manages waitcnt)
        const float* p = xsrcP + DD;
        #pragma unroll
        for (int kt = 0; kt < 4; ++kt) {
            S[2 * kt]     = *(const float4*)(p + kt * 32);
            S[2 * kt + 1] = *(const float4*)(p + kt * 32 + 4);
        }
    }
    __syncthreads();

    // ---------------- scan ----------------
    for (int t = 0; t < TT; ++t) {
        const int slot = t & 1, nslot = slot ^ 1;
        bf16x8 xfp[4];       // producer ff fragments (live A->B)
        f32x4 zsave[2];      // consumer z (live A->B)

        if (cons) {
            // ===== consumer phase A: recurrent z/r + sigmoid + rh =====
            f32x4 az[2], ar[2];
            #pragma unroll
            for (int ct = 0; ct < 2; ++ct) {
                az[ct] = *(const f32x4*)&pff[slot][0][c][oc[ct]];
                ar[ct] = *(const f32x4*)&pff[slot][1][c][oc[ct]];
            }
            bf16x8 hf[4];
            #pragma unroll
            for (int kt = 0; kt < 4; ++kt) hf[kt] = hrow[fg[kt]];
            #pragma unroll
            for (int kt = 0; kt < 4; ++kt)
                #pragma unroll
                for (int ct = 0; ct < 2; ++ct) {
                    az[ct] = MFMA16(W[0][kt][ct], hf[kt], az[ct], 0, 0, 0);
                    ar[ct] = MFMA16(W[1][kt][ct], hf[kt], ar[ct], 0, 0, 0);
                }
            #pragma unroll
            for (int ct = 0; ct < 2; ++ct) {
                f32x4 rhv;
                #pragma unroll
                for (int r = 0; r < 4; ++r) {
                    zsave[ct][r] = sigm(az[ct][r]);
                    rhv[r]       = sigm(ar[ct][r]) * hreg[ct][r];
                }
                *(uint2*)((short*)&rhbuf[c][gout[ct]] + ohalf) =
                    make_uint2(pk2(rhv[0], rhv[1]), pk2(rhv[2], rhv[3]));
            }
        } else {
            // ===== producer phase A: cvt x(t+1), prefetch x(t+2), ff z/r =====
            #pragma unroll
            for (int kt = 0; kt < 4; ++kt) xfp[kt] = mk8(S[2 * kt], S[2 * kt + 1]);
            {
                const int tn = (t + 2 < TT) ? t + 2 : TT - 1;
                const float* p = xsrcP + (size_t)tn * DD;
                #pragma unroll
                for (int kt = 0; kt < 4; ++kt) {
                    S[2 * kt]     = *(const float4*)(p + kt * 32);
                    S[2 * kt + 1] = *(const float4*)(p + kt * 32 + 4);
                }
            }
            f32x4 paz[2], par[2];
            #pragma unroll
            for (int ct = 0; ct < 2; ++ct) {
                paz[ct] = *(const f32x4*)&biasLDS[0][oc[ct]];
                par[ct] = *(const f32x4*)&biasLDS[1][oc[ct]];
            }
            #pragma unroll
            for (int kt = 0; kt < 4; ++kt)
                #pragma unroll
                for (int ct = 0; ct < 2; ++ct) {
                    paz[ct] = MFMA16(W[0][kt][ct], xfp[kt], paz[ct], 0, 0, 0);
                    par[ct] = MFMA16(W[1][kt][ct], xfp[kt], par[ct], 0, 0, 0);
                }
            #pragma unroll
            for (int ct = 0; ct < 2; ++ct) {
                *(f32x4*)&pff[nslot][0][c][oc[ct]] = paz[ct];
                *(f32x4*)&pff[nslot][1][c][oc[ct]] = par[ct];
            }
        }
        bar_lds();
        if (cons) {
            // ===== consumer phase B: h_tilde + update + h exchange =====
            f32x4 ah[2];
            #pragma unroll
            for (int ct = 0; ct < 2; ++ct)
                ah[ct] = *(const f32x4*)&pff[slot][2][c][oc[ct]];
            bf16x8 rf[4];
            #pragma unroll
            for (int kt = 0; kt < 4; ++kt) rf[kt] = rhrow[fg[kt]];
            #pragma unroll
            for (int kt = 0; kt < 4; ++kt)
                #pragma unroll
                for (int ct = 0; ct < 2; ++ct)
                    ah[ct] = MFMA16(W[2][kt][ct], rf[kt], ah[ct], 0, 0, 0);
            const float a_c = attbuf[c][t];
            #pragma unroll
            for (int ct = 0; ct < 2; ++ct) {
                #pragma unroll
                for (int r = 0; r < 4; ++r) {
                    float ht = tanhf_(ah[ct][r]);
                    float zp = a_c * zsave[ct][r];
                    hreg[ct][r] = __builtin_fmaf(zp, ht - hreg[ct][r], hreg[ct][r]);
                }
                *(uint2*)((short*)&hbuf[c][gout[ct]] + ohalf) =
                    make_uint2(pk2(hreg[ct][0], hreg[ct][1]), pk2(hreg[ct][2], hreg[ct][3]));
            }
        } else {
            // ===== producer phase B: ff h-gate =====
            f32x4 pah[2];
            #pragma unroll
            for (int ct = 0; ct < 2; ++ct)
                pah[ct] = *(const f32x4*)&biasLDS[2][oc[ct]];
            #pragma unroll
            for (int kt = 0; kt < 4; ++kt)
                #pragma unroll
                for (int ct = 0; ct < 2; ++ct)
                    pah[ct] = MFMA16(W[2][kt][ct], xfp[kt], pah[ct], 0, 0, 0);
            #pragma unroll
            for (int ct = 0; ct < 2; ++ct)
                *(f32x4*)&pff[nslot][2][c][oc[ct]] = pah[ct];
        }
        bar_lds();
    }

    // ---------------- store h_final (consumers) ----------------
    if (cons) {
        #pragma unroll
        for (int ct = 0; ct < 2; ++ct) {
            float4 o; o.x = hreg[ct][0]; o.y = hreg[ct][1]; o.z = hreg[ct][2]; o.w = hreg[ct][3];
            *(float4*)&out[(size_t)(rowbase + c) * HH + oc[ct]] = o;
        }
    }
}

extern "C" void kernel_launch(void* const* d_in, const int* in_sizes, int n_in,
                              void* d_out, int out_size, void* d_ws, size_t ws_size,
                              hipStream_t stream) {
    const float* inp = (const float*)d_in[0];
    const float* att = (const float*)d_in[1];
    const float* h0  = (const float*)d_in[2];
    const float* Wz  = (const float*)d_in[3];
    const float* bz  = (const float*)d_in[4];
    const float* Wr  = (const float*)d_in[5];
    const float* br  = (const float*)d_in[6];
    const float* Wh  = (const float*)d_in[7];
    const float* bh  = (const float*)d_in[8];
    float* out = (float*)d_out;

    dim3 grid(BB / 16), block(512);
    augru_kernel<<<grid, block, 0, stream>>>(inp, att, h0, Wz, bz, Wr, br, Wh, bh, out);
}